// Round 7
// baseline (163.667 us; speedup 1.0000x reference)
//
#include <hip/hip_runtime.h>
#include <cstdint>
#include <cstddef>

// ---------------------------------------------------------------------------
// QLSTM on MI355X.
//
// Math: qlayer(ang)[w] = prod_{v in S_w} cos(ang_v), S_w from the GF(2)-linear
// CNOT-ring permutation (DEPTH=2, 8 qubits, wire0=MSB). Verified 3x.
// Packed little-endian byte-per-wire: 0x55AAD5EAF5FAFDAB.
//
// R3: scan 72us (libm on chain). R4: native v_cos/v_exp/v_rcp -> 47.5us
// (~890cy/step: 3 ds_swizzle round-trips ~160cy each on the serial chain).
// R6: lane relayout (g0|w<<1|g1<<4) -> wire exchanges become DPP lane-XOR
// (VALU latency); only ONE ds_swizzle round trip (lane^16) per step remains.
// ---------------------------------------------------------------------------

constexpr int SEQ    = 128;
constexpr int NBATCH = 512;
constexpr int INDIM  = 64;
constexpr int FANIN  = 72;   // INPUT_DIM + HIDDEN_DIM
constexpr long OUT_HX = (long)SEQ * NBATCH * 8;
constexpr long OUT_CX = OUT_HX + (long)NBATCH * 8;

#define SWZ(v, imm) __int_as_float(__builtin_amdgcn_ds_swizzle(__float_as_int(v), (imm)))

__device__ __forceinline__ float fast_cos(float ang) {
    // cos(ang) = v_cos(fract(ang / 2pi)); v_cos takes revolutions in [0,1).
    const float rev = ang * 0.15915494309189535f;
    return __builtin_amdgcn_cosf(__builtin_amdgcn_fractf(rev));
}

// DPP lane-XOR moves (within 16-lane DPP rows; our patterns never cross rows).
template <int CTRL> __device__ __forceinline__ float DPPF(float x) {
    return __int_as_float(__builtin_amdgcn_update_dpp(
        0, __float_as_int(x), CTRL, 0xF, 0xF, false));
}
__device__ __forceinline__ float xlane1(float x) { return DPPF<0xB1>(x); }  // quad_perm[1,0,3,2]
__device__ __forceinline__ float xlane2(float x) { return DPPF<0x4E>(x); }  // quad_perm[2,3,0,1]
__device__ __forceinline__ float xlane4(float x) { return DPPF<0x141>(DPPF<0x1B>(x)); } // XOR3 then XOR7
__device__ __forceinline__ float xlane8(float x) { return DPPF<0x128>(x); } // row_ror:8 == lane^8

// ---------------------------------------------------------------------------
// Kernel A: xp[t*512+b][g*8+w] = sum_k x[t,b,k]*W_g[w,k] + b_g[w] + th_g[w]
// (unchanged from R4: register-tiled, ~few us, not in top-5)
// ---------------------------------------------------------------------------
__global__ __launch_bounds__(256) void xproj_kernel(
    const float* __restrict__ x,
    const float* __restrict__ Wf, const float* __restrict__ bf, const float* __restrict__ thf,
    const float* __restrict__ Wi, const float* __restrict__ bi, const float* __restrict__ thi,
    const float* __restrict__ Wu, const float* __restrict__ bu, const float* __restrict__ thu,
    const float* __restrict__ Wo, const float* __restrict__ bo, const float* __restrict__ tho,
    float* __restrict__ xp)
{
    __shared__ float lx[128 * 68];
    __shared__ float lbias[32];
    const int tid = threadIdx.x;
    const long rowBase = (long)blockIdx.x * 128;

    if (tid < 32) {
        const int g = tid >> 3, w = tid & 7;
        const float* bg = (g == 0) ? bf : (g == 1) ? bi : (g == 2) ? bu : bo;
        const float* tg = (g == 0) ? thf : (g == 1) ? thi : (g == 2) ? thu : tho;
        lbias[tid] = bg[w] + tg[w];
    }

    const float4* xin = reinterpret_cast<const float4*>(x + rowBase * INDIM);
#pragma unroll
    for (int i = 0; i < 8; ++i) {
        const int f   = i * 256 + tid;
        const int row = f >> 4;
        const int kq  = f & 15;
        *reinterpret_cast<float4*>(&lx[row * 68 + kq * 4]) = xin[f];
    }
    __syncthreads();

    const int og = tid & 3;
    const int q  = tid >> 2;
    const float* Wg = (og == 0) ? Wf : (og == 1) ? Wi : (og == 2) ? Wu : Wo;

    float acc[2][8];
#pragma unroll
    for (int r = 0; r < 2; ++r)
#pragma unroll
        for (int j = 0; j < 8; ++j) acc[r][j] = 0.f;

#pragma unroll
    for (int k4 = 0; k4 < 16; ++k4) {
        const float4 x0 = *reinterpret_cast<const float4*>(&lx[q * 68 + k4 * 4]);
        const float4 x1 = *reinterpret_cast<const float4*>(&lx[(q + 64) * 68 + k4 * 4]);
#pragma unroll
        for (int j = 0; j < 8; ++j) {
            const float4 wv = *reinterpret_cast<const float4*>(Wg + j * FANIN + k4 * 4);
            acc[0][j] = fmaf(x0.x, wv.x, acc[0][j]);
            acc[0][j] = fmaf(x0.y, wv.y, acc[0][j]);
            acc[0][j] = fmaf(x0.z, wv.z, acc[0][j]);
            acc[0][j] = fmaf(x0.w, wv.w, acc[0][j]);
            acc[1][j] = fmaf(x1.x, wv.x, acc[1][j]);
            acc[1][j] = fmaf(x1.y, wv.y, acc[1][j]);
            acc[1][j] = fmaf(x1.z, wv.z, acc[1][j]);
            acc[1][j] = fmaf(x1.w, wv.w, acc[1][j]);
        }
    }

#pragma unroll
    for (int r = 0; r < 2; ++r) {
        float4 o0, o1;
        o0.x = acc[r][0] + lbias[og * 8 + 0];
        o0.y = acc[r][1] + lbias[og * 8 + 1];
        o0.z = acc[r][2] + lbias[og * 8 + 2];
        o0.w = acc[r][3] + lbias[og * 8 + 3];
        o1.x = acc[r][4] + lbias[og * 8 + 4];
        o1.y = acc[r][5] + lbias[og * 8 + 5];
        o1.z = acc[r][6] + lbias[og * 8 + 6];
        o1.w = acc[r][7] + lbias[og * 8 + 7];
        float* dst = xp + (rowBase + q + 64 * r) * 32 + og * 8;
        reinterpret_cast<float4*>(dst)[0] = o0;
        reinterpret_cast<float4*>(dst)[1] = o1;
    }
}

// ---------------------------------------------------------------------------
// Kernel B (R6): lane = g0 | w<<1 | g1<<4  (g = g0 + 2*g1, w = (lane>>1)&7).
// Wire-axis exchanges (w^1,w^2,w^4 <-> lane^2,^4,^8) via DPP butterflies;
// gate-axis: g^1 via DPP lane^1, g^2 via ONE ds_swizzle xor=0x10 round trip.
// Per-lane precomputed: pm[d] = S_w contains (w^d); whx[d] = W_g[w][64+(w^d)].
// ---------------------------------------------------------------------------
__global__ __launch_bounds__(256) void qlstm_scan_kernel(
    const float* __restrict__ xp,
    const float* __restrict__ Wf, const float* __restrict__ Wi,
    const float* __restrict__ Wu, const float* __restrict__ Wo,
    float* __restrict__ out)
{
    const int tid  = threadIdx.x;
    const int lane = tid & 31;
    const int row  = (blockIdx.x << 3) + (tid >> 5);   // batch index 0..511
    const int g    = (lane & 1) | ((lane >> 3) & 2);
    const int w    = (lane >> 1) & 7;

    const float* Wg = (g == 0) ? Wf : (g == 1) ? Wi : (g == 2) ? Wu : Wo;

    // hidden weights in XOR-distance order: whx[d] = W_g[w][64 + (w^d)]
    float whx[8];
#pragma unroll
    for (int d = 0; d < 8; ++d) whx[d] = Wg[w * FANIN + 64 + (w ^ d)];

    const unsigned mask = (unsigned)((0x55AAD5EAF5FAFDABull >> (w * 8)) & 0xFFull);
    bool pm[8];
#pragma unroll
    for (int d = 0; d < 8; ++d) pm[d] = ((mask >> (w ^ d)) & 1u) != 0u;

    // activation constants (loop-invariant; v_cmp for selects hoisted too)
    const bool  isU  = (g == 2);
    const float ZL   = isU ? -2.0f : -1.0f;
    const float A    = isU ?  2.0f :  1.0f;
    const float B    = isU ? -1.0f :  0.0f;
    const bool  gOdd = (lane & 1) != 0;
    const bool  gHi  = (lane & 16) != 0;

    const int col = g * 8 + w;     // xp column (gate-major, as written by xproj)

    float hh0=0.f,hh1=0.f,hh2=0.f,hh3=0.f,hh4=0.f,hh5=0.f,hh6=0.f,hh7=0.f;
    float cxl = 0.f;

    // two-deep rolling prefetch of the x-projection
    float xv0 = xp[(long)row * 32 + col];
    float xv1 = xp[((long)NBATCH + row) * 32 + col];

    for (int t = 0; t < SEQ; ++t) {
        float xv2 = 0.f;
        if (t + 2 < SEQ) xv2 = xp[((long)(t + 2) * NBATCH + row) * 32 + col];

        // angle: xp + h.wh  (hh/whx in XOR-distance order)
        const float d0 = fmaf(hh0, whx[0], fmaf(hh1, whx[1], fmaf(hh2, whx[2], hh3 * whx[3])));
        const float d1 = fmaf(hh4, whx[4], fmaf(hh5, whx[5], fmaf(hh6, whx[6], hh7 * whx[7])));
        const float ang = xv0 + d0 + d1;

        const float c = fast_cos(ang);

        // wire all-gather butterfly via DPP: cc_d = c[w^d]
        const float cc0 = c;
        const float cc1 = xlane2(cc0);
        const float cc2 = xlane4(cc0);
        const float cc3 = xlane4(cc1);
        const float cc4 = xlane8(cc0);
        const float cc5 = xlane8(cc1);
        const float cc6 = xlane8(cc2);
        const float cc7 = xlane8(cc3);

        // subset product (masks pre-permuted to XOR-distance order)
        const float p0 = pm[0] ? cc0 : 1.0f;
        const float p1 = pm[1] ? cc1 : 1.0f;
        const float p2 = pm[2] ? cc2 : 1.0f;
        const float p3 = pm[3] ? cc3 : 1.0f;
        const float p4 = pm[4] ? cc4 : 1.0f;
        const float p5 = pm[5] ? cc5 : 1.0f;
        const float p6 = pm[6] ? cc6 : 1.0f;
        const float p7 = pm[7] ? cc7 : 1.0f;
        const float z = ((p0 * p1) * (p2 * p3)) * ((p4 * p5) * (p6 * p7));

        // activation (sigmoid for f,i,o; tanh for u), native exp/rcp
        const float e   = __expf(z * ZL);
        const float act = fmaf(A, __builtin_amdgcn_rcpf(1.0f + e), B);

        // gate gather: g^1 via DPP, g^2 via one ds_swizzle round trip
        const float a01 = xlane1(act);
        const float ae  = gOdd ? a01 : act;    // even gate of own pair
        const float ao  = gOdd ? act : a01;    // odd gate of own pair
        const float be  = SWZ(ae, 0x401F);     // lane^16: other pair, even
        const float bo  = SWZ(ao, 0x401F);     // lane^16: other pair, odd
        const float fg  = gHi ? be : ae;
        const float ig  = gHi ? bo : ao;
        const float ug  = gHi ? ae : be;
        const float og  = gHi ? ao : bo;

        // cell update (every lane owns wire w; replicated across its 4 gate lanes)
        const float ncx = fmaf(fg, cxl, ig * ug);
        const float et  = __expf(-2.0f * ncx);
        const float tc  = fmaf(2.0f, __builtin_amdgcn_rcpf(1.0f + et), -1.0f);
        const float nhx = og * tc;
        cxl = ncx;

        if ((lane & 0x11) == 0) out[((long)t * NBATCH + row) * 8 + w] = nhx;

        // h all-gather butterfly via DPP: hh_d = nhx[w^d]
        hh0 = nhx;
        hh1 = xlane2(hh0);
        hh2 = xlane4(hh0);
        hh3 = xlane4(hh1);
        hh4 = xlane8(hh0);
        hh5 = xlane8(hh1);
        hh6 = xlane8(hh2);
        hh7 = xlane8(hh3);

        xv0 = xv1; xv1 = xv2;
    }

    if ((lane & 0x11) == 0) {
        out[OUT_HX + (long)row * 8 + w] = hh0;
        out[OUT_CX + (long)row * 8 + w] = cxl;
    }
}

// ---------------------------------------------------------------------------
// FUSED fallback (ws too small): R4's proven kernel, old 32-lane layout.
// ---------------------------------------------------------------------------
__global__ __launch_bounds__(256) void qlstm_scan_fused(
    const float* __restrict__ x,
    const float* __restrict__ Wf, const float* __restrict__ bf, const float* __restrict__ thf,
    const float* __restrict__ Wi, const float* __restrict__ bi, const float* __restrict__ thi,
    const float* __restrict__ Wu, const float* __restrict__ bu, const float* __restrict__ thu,
    const float* __restrict__ Wo, const float* __restrict__ bo, const float* __restrict__ tho,
    float* __restrict__ out)
{
    const int tid  = threadIdx.x;
    const int lane = tid & 31;
    const int row  = (blockIdx.x << 3) + (tid >> 5);
    const int g    = lane >> 3;
    const int w    = lane & 7;

    const float* Wg = (g == 0) ? Wf : (g == 1) ? Wi : (g == 2) ? Wu : Wo;
    const float* bg = (g == 0) ? bf : (g == 1) ? bi : (g == 2) ? bu : bo;
    const float* tg = (g == 0) ? thf : (g == 1) ? thi : (g == 2) ? thu : tho;

    float wh0, wh1, wh2, wh3, wh4, wh5, wh6, wh7;
    {
        const float4* p = reinterpret_cast<const float4*>(Wg + w * FANIN + 64);
        const float4 a = p[0], b4 = p[1];
        wh0 = a.x; wh1 = a.y; wh2 = a.z; wh3 = a.w;
        wh4 = b4.x; wh5 = b4.y; wh6 = b4.z; wh7 = b4.w;
    }
    const float bias = bg[w] + tg[w];
    float wx[64];
#pragma unroll
    for (int k4 = 0; k4 < 16; ++k4) {
        const float4 v = reinterpret_cast<const float4*>(Wg + w * FANIN)[k4];
        wx[4*k4+0] = v.x; wx[4*k4+1] = v.y; wx[4*k4+2] = v.z; wx[4*k4+3] = v.w;
    }

    const unsigned mask = (unsigned)((0x55AAD5EAF5FAFDABull >> (w * 8)) & 0xFFull);
    const bool  isU = (g == 2);
    const float ZL  = isU ? -2.0f : -1.0f;
    const float A   = isU ?  2.0f :  1.0f;
    const float B   = isU ? -1.0f :  0.0f;

    float h0=0,h1=0,h2=0,h3=0,h4=0,h5=0,h6=0,h7=0, cxl=0, nhx=0;

    for (int t = 0; t < SEQ; ++t) {
        const float4* xr4 = reinterpret_cast<const float4*>(x + ((long)t * NBATCH + row) * INDIM);
        float acc = bias;
#pragma unroll
        for (int k4 = 0; k4 < 16; ++k4) {
            const float4 v = xr4[k4];
            acc = fmaf(v.x, wx[4*k4+0], acc);
            acc = fmaf(v.y, wx[4*k4+1], acc);
            acc = fmaf(v.z, wx[4*k4+2], acc);
            acc = fmaf(v.w, wx[4*k4+3], acc);
        }
        float ang = acc;
        ang += fmaf(h0, wh0, fmaf(h1, wh1, fmaf(h2, wh2, h3 * wh3)))
             + fmaf(h4, wh4, fmaf(h5, wh5, fmaf(h6, wh6, h7 * wh7)));

        const float c = fast_cos(ang);
        const float cb0 = SWZ(c, 0x018); const float cb1 = SWZ(c, 0x038);
        const float cb2 = SWZ(c, 0x058); const float cb3 = SWZ(c, 0x078);
        const float cb4 = SWZ(c, 0x098); const float cb5 = SWZ(c, 0x0B8);
        const float cb6 = SWZ(c, 0x0D8); const float cb7 = SWZ(c, 0x0F8);

        const float p0 = (mask & 0x01u) ? cb0 : 1.0f;
        const float p1 = (mask & 0x02u) ? cb1 : 1.0f;
        const float p2 = (mask & 0x04u) ? cb2 : 1.0f;
        const float p3 = (mask & 0x08u) ? cb3 : 1.0f;
        const float p4 = (mask & 0x10u) ? cb4 : 1.0f;
        const float p5 = (mask & 0x20u) ? cb5 : 1.0f;
        const float p6 = (mask & 0x40u) ? cb6 : 1.0f;
        const float p7 = (mask & 0x80u) ? cb7 : 1.0f;
        const float z = ((p0*p1)*(p2*p3)) * ((p4*p5)*(p6*p7));

        const float e   = __expf(z * ZL);
        const float act = fmaf(A, __builtin_amdgcn_rcpf(1.0f + e), B);

        const float fg = SWZ(act, 0x007);
        const float ig = SWZ(act, 0x107);
        const float ug = SWZ(act, 0x207);
        const float og = SWZ(act, 0x307);

        const float ncx = fmaf(fg, cxl, ig * ug);
        const float et  = __expf(-2.0f * ncx);
        const float tc  = fmaf(2.0f, __builtin_amdgcn_rcpf(1.0f + et), -1.0f);
        nhx = og * tc;
        cxl = ncx;

        if (lane < 8) out[((long)t * NBATCH + row) * 8 + lane] = nhx;

        h0 = SWZ(nhx, 0x000); h1 = SWZ(nhx, 0x020);
        h2 = SWZ(nhx, 0x040); h3 = SWZ(nhx, 0x060);
        h4 = SWZ(nhx, 0x080); h5 = SWZ(nhx, 0x0A0);
        h6 = SWZ(nhx, 0x0C0); h7 = SWZ(nhx, 0x0E0);
    }

    if (lane < 8) {
        out[OUT_HX + (long)row * 8 + lane] = nhx;
        out[OUT_CX + (long)row * 8 + lane] = cxl;
    }
}

// ---------------------------------------------------------------------------
extern "C" void kernel_launch(void* const* d_in, const int* in_sizes, int n_in,
                              void* d_out, int out_size, void* d_ws, size_t ws_size,
                              hipStream_t stream)
{
    const float* x = (const float*)d_in[0];

    const float *Wf, *bf, *thf, *Wi, *bi, *thi, *Wu, *bu, *thu, *Wo, *bo, *tho;
    if (in_sizes[3] == 8) {  // dict order: W_f,b_f,th_f, W_i,b_i,th_i, ...
        Wf = (const float*)d_in[1];  bf = (const float*)d_in[2];  thf = (const float*)d_in[3];
        Wi = (const float*)d_in[4];  bi = (const float*)d_in[5];  thi = (const float*)d_in[6];
        Wu = (const float*)d_in[7];  bu = (const float*)d_in[8];  thu = (const float*)d_in[9];
        Wo = (const float*)d_in[10]; bo = (const float*)d_in[11]; tho = (const float*)d_in[12];
    } else {                 // signature order
        Wf = (const float*)d_in[1];  bf = (const float*)d_in[2];
        Wi = (const float*)d_in[3];  bi = (const float*)d_in[4];
        Wu = (const float*)d_in[5];  bu = (const float*)d_in[6];
        Wo = (const float*)d_in[7];  bo = (const float*)d_in[8];
        thf = (const float*)d_in[9]; thi = (const float*)d_in[10];
        thu = (const float*)d_in[11]; tho = (const float*)d_in[12];
    }

    float* out = (float*)d_out;
    float* xp  = (float*)d_ws;
    const size_t need = (size_t)SEQ * NBATCH * 32 * sizeof(float);  // 8.4 MB

    if (ws_size >= need) {
        xproj_kernel<<<(SEQ * NBATCH) / 128, 256, 0, stream>>>(
            x, Wf, bf, thf, Wi, bi, thi, Wu, bu, thu, Wo, bo, tho, xp);
        qlstm_scan_kernel<<<NBATCH / 8, 256, 0, stream>>>(
            xp, Wf, Wi, Wu, Wo, out);
    } else {
        qlstm_scan_fused<<<NBATCH / 8, 256, 0, stream>>>(
            x, Wf, bf, thf, Wi, bi, thi, Wu, bu, thu, Wo, bo, tho, out);
    }
}

// Round 10
// 148.680 us; speedup vs baseline: 1.1008x; 1.1008x over previous
//
#include <hip/hip_runtime.h>
#include <cstdint>
#include <cstddef>

// ---------------------------------------------------------------------------
// QLSTM on MI355X.
//
// Math: qlayer(ang)[w] = prod_{v in S_w} cos(ang_v), S_w from the GF(2)-linear
// CNOT-ring permutation (DEPTH=2, 8 qubits, wire0=MSB). Verified 3x.
// Packed little-endian byte-per-wire: 0x55AAD5EAF5FAFDAB.
//
// R3: scan 72us (libm). R4: native cos/exp/rcp -> 47.5us. R6: DPP butterflies
// (removed 2/3 ds_swizzle groups) -> 46.2us NULL => swizzle latency was NOT
// the bottleneck. R8 theory: per-step xp global-load waitcnt on the chain +
// exposed latency at 1 wave/SIMD. Fix: (1) 16-step register-chunked xp preload
// (no loads in the step chain), (2) g1 on lane bit5 so the gate^2 exchange is
// v_permlane32_swap (no LDS ops at all in loop), (3) depth-2 butterflies.
// ---------------------------------------------------------------------------

constexpr int SEQ    = 128;
constexpr int NBATCH = 512;
constexpr int INDIM  = 64;
constexpr int FANIN  = 72;   // INPUT_DIM + HIDDEN_DIM
constexpr long OUT_HX = (long)SEQ * NBATCH * 8;
constexpr long OUT_CX = OUT_HX + (long)NBATCH * 8;

#define SWZ(v, imm) __int_as_float(__builtin_amdgcn_ds_swizzle(__float_as_int(v), (imm)))

__device__ __forceinline__ float fast_cos(float ang) {
    // cos(ang) = v_cos(fract(ang / 2pi)); v_cos takes revolutions in [0,1).
    const float rev = ang * 0.15915494309189535f;
    return __builtin_amdgcn_cosf(__builtin_amdgcn_fractf(rev));
}

// DPP helpers (proven in R6/R7 run). result[l] = x[l ^ XORMASK] per ctrl:
//   0xB1 quad_perm[1,0,3,2]=^1   0x4E quad_perm[2,3,0,1]=^2
//   0x1B quad_perm[3,2,1,0]=^3   0x141 ROW_HALF_MIRROR=^7
//   0x140 ROW_MIRROR=^15         0x128 ROW_ROR:8=^8   (all within 16-lane rows)
template <int CTRL> __device__ __forceinline__ float DPPF(float x) {
    return __int_as_float(__builtin_amdgcn_update_dpp(
        0, __float_as_int(x), CTRL, 0xF, 0xF, false));
}

// lane^32 exchange: v_permlane32_swap (gfx950). With both operands = x:
// r[0] = new_vdst = {x.lo, x.lo}, r[1] = new_src = {x.hi, x.hi}
// => x[l^32] = hiHalf ? r[0] : r[1].
__device__ __forceinline__ float xlane32(float x, bool hiHalf) {
#if __has_builtin(__builtin_amdgcn_permlane32_swap)
    typedef unsigned uint2v __attribute__((ext_vector_type(2)));
    uint2v r = __builtin_amdgcn_permlane32_swap(
        __float_as_uint(x), __float_as_uint(x), false, false);
    return __uint_as_float(hiHalf ? r[0] : r[1]);
#else
    (void)hiHalf;
    return __shfl_xor(x, 32, 64);   // ds_bpermute fallback (correct, slower)
#endif
}

// ---------------------------------------------------------------------------
// Kernel A: xp[t*512+b][g*8+w] = sum_k x[t,b,k]*W_g[w,k] + b_g[w] + th_g[w]
// (unchanged from R4: register-tiled; never appeared in top-5)
// ---------------------------------------------------------------------------
__global__ __launch_bounds__(256) void xproj_kernel(
    const float* __restrict__ x,
    const float* __restrict__ Wf, const float* __restrict__ bf, const float* __restrict__ thf,
    const float* __restrict__ Wi, const float* __restrict__ bi, const float* __restrict__ thi,
    const float* __restrict__ Wu, const float* __restrict__ bu, const float* __restrict__ thu,
    const float* __restrict__ Wo, const float* __restrict__ bo, const float* __restrict__ tho,
    float* __restrict__ xp)
{
    __shared__ float lx[128 * 68];
    __shared__ float lbias[32];
    const int tid = threadIdx.x;
    const long rowBase = (long)blockIdx.x * 128;

    if (tid < 32) {
        const int g = tid >> 3, w = tid & 7;
        const float* bg = (g == 0) ? bf : (g == 1) ? bi : (g == 2) ? bu : bo;
        const float* tg = (g == 0) ? thf : (g == 1) ? thi : (g == 2) ? thu : tho;
        lbias[tid] = bg[w] + tg[w];
    }

    const float4* xin = reinterpret_cast<const float4*>(x + rowBase * INDIM);
#pragma unroll
    for (int i = 0; i < 8; ++i) {
        const int f   = i * 256 + tid;
        const int row = f >> 4;
        const int kq  = f & 15;
        *reinterpret_cast<float4*>(&lx[row * 68 + kq * 4]) = xin[f];
    }
    __syncthreads();

    const int og = tid & 3;
    const int q  = tid >> 2;
    const float* Wg = (og == 0) ? Wf : (og == 1) ? Wi : (og == 2) ? Wu : Wo;

    float acc[2][8];
#pragma unroll
    for (int r = 0; r < 2; ++r)
#pragma unroll
        for (int j = 0; j < 8; ++j) acc[r][j] = 0.f;

#pragma unroll
    for (int k4 = 0; k4 < 16; ++k4) {
        const float4 x0 = *reinterpret_cast<const float4*>(&lx[q * 68 + k4 * 4]);
        const float4 x1 = *reinterpret_cast<const float4*>(&lx[(q + 64) * 68 + k4 * 4]);
#pragma unroll
        for (int j = 0; j < 8; ++j) {
            const float4 wv = *reinterpret_cast<const float4*>(Wg + j * FANIN + k4 * 4);
            acc[0][j] = fmaf(x0.x, wv.x, acc[0][j]);
            acc[0][j] = fmaf(x0.y, wv.y, acc[0][j]);
            acc[0][j] = fmaf(x0.z, wv.z, acc[0][j]);
            acc[0][j] = fmaf(x0.w, wv.w, acc[0][j]);
            acc[1][j] = fmaf(x1.x, wv.x, acc[1][j]);
            acc[1][j] = fmaf(x1.y, wv.y, acc[1][j]);
            acc[1][j] = fmaf(x1.z, wv.z, acc[1][j]);
            acc[1][j] = fmaf(x1.w, wv.w, acc[1][j]);
        }
    }

#pragma unroll
    for (int r = 0; r < 2; ++r) {
        float4 o0, o1;
        o0.x = acc[r][0] + lbias[og * 8 + 0];
        o0.y = acc[r][1] + lbias[og * 8 + 1];
        o0.z = acc[r][2] + lbias[og * 8 + 2];
        o0.w = acc[r][3] + lbias[og * 8 + 3];
        o1.x = acc[r][4] + lbias[og * 8 + 4];
        o1.y = acc[r][5] + lbias[og * 8 + 5];
        o1.z = acc[r][6] + lbias[og * 8 + 6];
        o1.w = acc[r][7] + lbias[og * 8 + 7];
        float* dst = xp + (rowBase + q + 64 * r) * 32 + og * 8;
        reinterpret_cast<float4*>(dst)[0] = o0;
        reinterpret_cast<float4*>(dst)[1] = o1;
    }
}

// ---------------------------------------------------------------------------
// Kernel B (R8): lane = g0 | w<<1 | rsub<<4 | g1<<5  (g = g0+2*g1).
// Wire exchanges: DPP within 16-lane rows (depth <= 2). g^1: DPP lane^1.
// g^2: permlane32_swap (lane^32). NO memory ops in the step chain; xp is
// preloaded in 16-step register chunks (double-buffered, static unroll).
// ---------------------------------------------------------------------------
__global__ __launch_bounds__(256) void qlstm_scan_kernel(
    const float* __restrict__ xp,
    const float* __restrict__ Wf, const float* __restrict__ Wi,
    const float* __restrict__ Wu, const float* __restrict__ Wo,
    float* __restrict__ out)
{
    const int tid  = threadIdx.x;
    const int lane = tid & 63;
    const int wv   = tid >> 6;                          // wave 0..3
    const int g1   = (lane >> 5) & 1;
    const int g    = (lane & 1) | (g1 << 1);
    const int w    = (lane >> 1) & 7;
    const int rsub = (lane >> 4) & 1;
    const int row  = (blockIdx.x << 3) + (wv << 1) + rsub;   // 0..511

    const float* Wg = (g == 0) ? Wf : (g == 1) ? Wi : (g == 2) ? Wu : Wo;

    // hidden weights in XOR-distance order: whx[d] = W_g[w][64 + (w^d)]
    float whx[8];
#pragma unroll
    for (int d = 0; d < 8; ++d) whx[d] = Wg[w * FANIN + 64 + (w ^ d)];

    const unsigned mask = (unsigned)((0x55AAD5EAF5FAFDABull >> (w * 8)) & 0xFFull);
    bool pm[8];
#pragma unroll
    for (int d = 0; d < 8; ++d) pm[d] = ((mask >> (w ^ d)) & 1u) != 0u;

    const bool  isU   = (g == 2);
    const float ZL    = isU ? -2.0f : -1.0f;
    const float A     = isU ?  2.0f :  1.0f;
    const float B     = isU ? -1.0f :  0.0f;
    const bool  gOdd  = (lane & 1) != 0;
    const bool  gHi   = g1 != 0;           // == hiHalf (bit 5)
    const bool  doOut = (lane & 0x21) == 0;

    const int col = g * 8 + w;             // xp column (gate-major)

    float hh0=0.f,hh1=0.f,hh2=0.f,hh3=0.f,hh4=0.f,hh5=0.f,hh6=0.f,hh7=0.f;
    float cxl = 0.f;

#define QSTEP(XV, T) do {                                                      \
    const float d0_ = fmaf(hh0, whx[0], fmaf(hh1, whx[1], fmaf(hh2, whx[2], hh3 * whx[3]))); \
    const float d1_ = fmaf(hh4, whx[4], fmaf(hh5, whx[5], fmaf(hh6, whx[6], hh7 * whx[7]))); \
    const float ang_ = (XV) + d0_ + d1_;                                       \
    const float c0_ = fast_cos(ang_);                                          \
    const float c1_ = DPPF<0x4E>(c0_);                                         \
    const float c2_ = DPPF<0x141>(DPPF<0x1B>(c0_));                            \
    const float c3_ = DPPF<0x141>(DPPF<0xB1>(c0_));                            \
    const float c4_ = DPPF<0x128>(c0_);                                        \
    const float c5_ = DPPF<0x128>(DPPF<0x4E>(c0_));                            \
    const float c6_ = DPPF<0x140>(DPPF<0x1B>(c0_));                            \
    const float c7_ = DPPF<0x140>(DPPF<0xB1>(c0_));                            \
    const float z_ = (((pm[0]?c0_:1.0f)*(pm[1]?c1_:1.0f))                      \
                    * ((pm[2]?c2_:1.0f)*(pm[3]?c3_:1.0f)))                     \
                   * (((pm[4]?c4_:1.0f)*(pm[5]?c5_:1.0f))                      \
                    * ((pm[6]?c6_:1.0f)*(pm[7]?c7_:1.0f)));                    \
    const float e_   = __expf(z_ * ZL);                                        \
    const float act_ = fmaf(A, __builtin_amdgcn_rcpf(1.0f + e_), B);           \
    const float a01_ = DPPF<0xB1>(act_);                                       \
    const float ae_  = gOdd ? a01_ : act_;                                     \
    const float ao_  = gOdd ? act_ : a01_;                                     \
    const float be_  = xlane32(ae_, gHi);                                      \
    const float bo_  = xlane32(ao_, gHi);                                      \
    const float fg_  = gHi ? be_ : ae_;                                        \
    const float ig_  = gHi ? bo_ : ao_;                                        \
    const float ug_  = gHi ? ae_ : be_;                                        \
    const float og_  = gHi ? ao_ : bo_;                                        \
    const float ncx_ = fmaf(fg_, cxl, ig_ * ug_);                              \
    const float et_  = __expf(-2.0f * ncx_);                                   \
    const float tc_  = fmaf(2.0f, __builtin_amdgcn_rcpf(1.0f + et_), -1.0f);   \
    const float nhx_ = og_ * tc_;                                              \
    cxl = ncx_;                                                                \
    if (doOut) out[((long)(T) * NBATCH + row) * 8 + w] = nhx_;                 \
    hh0 = nhx_;                                                                \
    hh1 = DPPF<0x4E>(nhx_);                                                    \
    hh2 = DPPF<0x141>(DPPF<0x1B>(nhx_));                                       \
    hh3 = DPPF<0x141>(DPPF<0xB1>(nhx_));                                       \
    hh4 = DPPF<0x128>(nhx_);                                                   \
    hh5 = DPPF<0x128>(DPPF<0x4E>(nhx_));                                       \
    hh6 = DPPF<0x140>(DPPF<0x1B>(nhx_));                                       \
    hh7 = DPPF<0x140>(DPPF<0xB1>(nhx_));                                       \
} while (0)

    // 16-step register chunks, double-buffered; all indices static (rule #20).
    float xva[16], xvb[16];
#pragma unroll
    for (int j = 0; j < 16; ++j)
        xva[j] = xp[((long)j * NBATCH + row) * 32 + col];

#pragma unroll 1
    for (int ck = 0; ck < 8; ++ck) {
        const int t0 = ck * 16;
        if (ck < 7) {
#pragma unroll
            for (int j = 0; j < 16; ++j)
                xvb[j] = xp[((long)(t0 + 16 + j) * NBATCH + row) * 32 + col];
        }
#pragma unroll
        for (int j = 0; j < 16; ++j) {
            QSTEP(xva[j], t0 + j);
        }
#pragma unroll
        for (int j = 0; j < 16; ++j) xva[j] = xvb[j];
    }
#undef QSTEP

    if (doOut) {
        out[OUT_HX + (long)row * 8 + w] = hh0;
        out[OUT_CX + (long)row * 8 + w] = cxl;
    }
}

// ---------------------------------------------------------------------------
// FUSED fallback (ws too small): R4's proven kernel, old 32-lane layout.
// ---------------------------------------------------------------------------
__global__ __launch_bounds__(256) void qlstm_scan_fused(
    const float* __restrict__ x,
    const float* __restrict__ Wf, const float* __restrict__ bf, const float* __restrict__ thf,
    const float* __restrict__ Wi, const float* __restrict__ bi, const float* __restrict__ thi,
    const float* __restrict__ Wu, const float* __restrict__ bu, const float* __restrict__ thu,
    const float* __restrict__ Wo, const float* __restrict__ bo, const float* __restrict__ tho,
    float* __restrict__ out)
{
    const int tid  = threadIdx.x;
    const int lane = tid & 31;
    const int row  = (blockIdx.x << 3) + (tid >> 5);
    const int g    = lane >> 3;
    const int w    = lane & 7;

    const float* Wg = (g == 0) ? Wf : (g == 1) ? Wi : (g == 2) ? Wu : Wo;
    const float* bg = (g == 0) ? bf : (g == 1) ? bi : (g == 2) ? bu : bo;
    const float* tg = (g == 0) ? thf : (g == 1) ? thi : (g == 2) ? thu : tho;

    float wh0, wh1, wh2, wh3, wh4, wh5, wh6, wh7;
    {
        const float4* p = reinterpret_cast<const float4*>(Wg + w * FANIN + 64);
        const float4 a = p[0], b4 = p[1];
        wh0 = a.x; wh1 = a.y; wh2 = a.z; wh3 = a.w;
        wh4 = b4.x; wh5 = b4.y; wh6 = b4.z; wh7 = b4.w;
    }
    const float bias = bg[w] + tg[w];
    float wx[64];
#pragma unroll
    for (int k4 = 0; k4 < 16; ++k4) {
        const float4 v = reinterpret_cast<const float4*>(Wg + w * FANIN)[k4];
        wx[4*k4+0] = v.x; wx[4*k4+1] = v.y; wx[4*k4+2] = v.z; wx[4*k4+3] = v.w;
    }

    const unsigned mask = (unsigned)((0x55AAD5EAF5FAFDABull >> (w * 8)) & 0xFFull);
    const bool  isU = (g == 2);
    const float ZL  = isU ? -2.0f : -1.0f;
    const float A   = isU ?  2.0f :  1.0f;
    const float B   = isU ? -1.0f :  0.0f;

    float h0=0,h1=0,h2=0,h3=0,h4=0,h5=0,h6=0,h7=0, cxl=0, nhx=0;

    for (int t = 0; t < SEQ; ++t) {
        const float4* xr4 = reinterpret_cast<const float4*>(x + ((long)t * NBATCH + row) * INDIM);
        float acc = bias;
#pragma unroll
        for (int k4 = 0; k4 < 16; ++k4) {
            const float4 v = xr4[k4];
            acc = fmaf(v.x, wx[4*k4+0], acc);
            acc = fmaf(v.y, wx[4*k4+1], acc);
            acc = fmaf(v.z, wx[4*k4+2], acc);
            acc = fmaf(v.w, wx[4*k4+3], acc);
        }
        float ang = acc;
        ang += fmaf(h0, wh0, fmaf(h1, wh1, fmaf(h2, wh2, h3 * wh3)))
             + fmaf(h4, wh4, fmaf(h5, wh5, fmaf(h6, wh6, h7 * wh7)));

        const float c = fast_cos(ang);
        const float cb0 = SWZ(c, 0x018); const float cb1 = SWZ(c, 0x038);
        const float cb2 = SWZ(c, 0x058); const float cb3 = SWZ(c, 0x078);
        const float cb4 = SWZ(c, 0x098); const float cb5 = SWZ(c, 0x0B8);
        const float cb6 = SWZ(c, 0x0D8); const float cb7 = SWZ(c, 0x0F8);

        const float p0 = (mask & 0x01u) ? cb0 : 1.0f;
        const float p1 = (mask & 0x02u) ? cb1 : 1.0f;
        const float p2 = (mask & 0x04u) ? cb2 : 1.0f;
        const float p3 = (mask & 0x08u) ? cb3 : 1.0f;
        const float p4 = (mask & 0x10u) ? cb4 : 1.0f;
        const float p5 = (mask & 0x20u) ? cb5 : 1.0f;
        const float p6 = (mask & 0x40u) ? cb6 : 1.0f;
        const float p7 = (mask & 0x80u) ? cb7 : 1.0f;
        const float z = ((p0*p1)*(p2*p3)) * ((p4*p5)*(p6*p7));

        const float e   = __expf(z * ZL);
        const float act = fmaf(A, __builtin_amdgcn_rcpf(1.0f + e), B);

        const float fg = SWZ(act, 0x007);
        const float ig = SWZ(act, 0x107);
        const float ug = SWZ(act, 0x207);
        const float og = SWZ(act, 0x307);

        const float ncx = fmaf(fg, cxl, ig * ug);
        const float et  = __expf(-2.0f * ncx);
        const float tc  = fmaf(2.0f, __builtin_amdgcn_rcpf(1.0f + et), -1.0f);
        nhx = og * tc;
        cxl = ncx;

        if (lane < 8) out[((long)t * NBATCH + row) * 8 + lane] = nhx;

        h0 = SWZ(nhx, 0x000); h1 = SWZ(nhx, 0x020);
        h2 = SWZ(nhx, 0x040); h3 = SWZ(nhx, 0x060);
        h4 = SWZ(nhx, 0x080); h5 = SWZ(nhx, 0x0A0);
        h6 = SWZ(nhx, 0x0C0); h7 = SWZ(nhx, 0x0E0);
    }

    if (lane < 8) {
        out[OUT_HX + (long)row * 8 + lane] = nhx;
        out[OUT_CX + (long)row * 8 + lane] = cxl;
    }
}

// ---------------------------------------------------------------------------
extern "C" void kernel_launch(void* const* d_in, const int* in_sizes, int n_in,
                              void* d_out, int out_size, void* d_ws, size_t ws_size,
                              hipStream_t stream)
{
    const float* x = (const float*)d_in[0];

    const float *Wf, *bf, *thf, *Wi, *bi, *thi, *Wu, *bu, *thu, *Wo, *bo, *tho;
    if (in_sizes[3] == 8) {  // dict order: W_f,b_f,th_f, W_i,b_i,th_i, ...
        Wf = (const float*)d_in[1];  bf = (const float*)d_in[2];  thf = (const float*)d_in[3];
        Wi = (const float*)d_in[4];  bi = (const float*)d_in[5];  thi = (const float*)d_in[6];
        Wu = (const float*)d_in[7];  bu = (const float*)d_in[8];  thu = (const float*)d_in[9];
        Wo = (const float*)d_in[10]; bo = (const float*)d_in[11]; tho = (const float*)d_in[12];
    } else {                 // signature order
        Wf = (const float*)d_in[1];  bf = (const float*)d_in[2];
        Wi = (const float*)d_in[3];  bi = (const float*)d_in[4];
        Wu = (const float*)d_in[5];  bu = (const float*)d_in[6];
        Wo = (const float*)d_in[7];  bo = (const float*)d_in[8];
        thf = (const float*)d_in[9]; thi = (const float*)d_in[10];
        thu = (const float*)d_in[11]; tho = (const float*)d_in[12];
    }

    float* out = (float*)d_out;
    float* xp  = (float*)d_ws;
    const size_t need = (size_t)SEQ * NBATCH * 32 * sizeof(float);  // 8.4 MB

    if (ws_size >= need) {
        xproj_kernel<<<(SEQ * NBATCH) / 128, 256, 0, stream>>>(
            x, Wf, bf, thf, Wi, bi, thi, Wu, bu, thu, Wo, bo, tho, xp);
        qlstm_scan_kernel<<<NBATCH / 8, 256, 0, stream>>>(
            xp, Wf, Wi, Wu, Wo, out);
    } else {
        qlstm_scan_fused<<<NBATCH / 8, 256, 0, stream>>>(
            x, Wf, bf, thf, Wi, bi, thi, Wu, bu, thu, Wo, bo, tho, out);
    }
}